// Round 12
// baseline (188.301 us; speedup 1.0000x reference)
//
#include <hip/hip_runtime.h>
#include <hip/hip_bf16.h>

// HierarchicalAttention: B=4,T=50,D=512, SRC=400, SENTS=16, WORDS=40.
// 3-launch pipeline:
//   kA   projections via bf16 MFMA with INLINE weight transpose (624 blocks;
//        Mt/bank-transpose REMOVED — context is now a GEMV on original banks)
//   k2   tanh scores — R7's 5280-block wave-fifth split (proven)
//   k3ac FUSED hier-combine + mask + softmax + f32 context GEMV, one block per
//        (b,t). Key fact: C[b][t][d] depends only on softmax row t, so the
//        fusion keeps 200 blocks and computes each softmax exactly once
//        (unlike R4's 64-block fusion). Masked slots have exactly-0.0
//        probability (exp underflow), so the GEMV iterates lengths rounded up
//        to 4 bit-exactly. f32 x f32 context — no Mt, no bf16 P, no MFMA tail.

#define B_    4
#define T_    50
#define D_    512
#define SRC_  400
#define SENTS_ 16
#define WORDS_ 40
#define NW_   640      // SENTS*WORDS
#define NMEM_ 1040     // SRC + NW
#define NJOB_ 1056     // NMEM + SENTS (score jobs per batch)

#define C2L2E 2.8853900817779268f   // 2*log2(e): x -> exp2(C2L2E*x) = exp(2x)

typedef unsigned short ushort_t;
using s8v = __attribute__((ext_vector_type(8))) short;   // 8 bf16 (4 VGPRs)
using f4v = __attribute__((ext_vector_type(4))) float;   // MFMA accumulator

// ---- workspace layout ----
// f32 region (float offsets):
#define OFF_WQ_WORD 0
#define OFF_WQ_SENT 102400
#define OFF_WQ_PASS 204800
#define OFF_UH_SRC  307200
#define OFF_UH_WORD 1126400
#define OFF_UH_SENT 2437120
#define OFF_SC_SRC  2469888
#define OFF_SC_WORD 2549888
#define OFF_SC_SENT 2677888

__device__ __forceinline__ ushort_t f2b(float f) {
    __hip_bfloat16 h = __float2bfloat16(f);   // RNE
    return *(ushort_t*)&h;
}

// ---------------- kA: projections with inline weight transpose ----------------
// 624 compact GEMM blocks (z0-2: 32 each M=200, z3: 320 M=2560, z4: 200 M=1600,
// z5: 8 M=64). Block tile 64x64, K=512 in 16 steps. Per step, the W[k][n] f32
// tile is staged to LDS (Wtmp, col-swizzled), transposed + converted to bf16 Bt
// in-block; A rows converted to At. 2 barriers/step; A and W global loads
// register-prefetched 2 steps ahead. Same RNE conversion point as k0f+k1.
__global__ __launch_bounds__(256) void kA(
    const float* __restrict__ source, const float* __restrict__ src_bank,
    const float* __restrict__ qa_sent_bank, const float* __restrict__ qa_word_bank,
    const float* __restrict__ w0, const float* __restrict__ w1,
    const float* __restrict__ w2, const float* __restrict__ w3,
    const float* __restrict__ w4, const float* __restrict__ w5,
    const float* __restrict__ bq_word, const float* __restrict__ bq_sent,
    const float* __restrict__ bq_pass,
    float* __restrict__ wsf)
{
    __shared__ float smemf[4224];   // At[0,1024) Bt[1024,2048) Wtmp[2048,4224)
    int bid = blockIdx.x;
    int tid = threadIdx.x;

    int z, rem;
    if (bid < 96)       { z = bid >> 5; rem = bid & 31; }
    else if (bid < 416) { z = 3; rem = bid - 96; }
    else if (bid < 616) { z = 4; rem = bid - 416; }
    else                { z = 5; rem = bid - 616; }
    int by = rem >> 3, bx = rem & 7;
    int M, atype; const float* bias; const float* W; float* C;
    switch (z) {
        case 0: M = 200;  atype = 0; bias = bq_word; W = w0; C = wsf + OFF_WQ_WORD; break;
        case 1: M = 200;  atype = 0; bias = bq_sent; W = w1; C = wsf + OFF_WQ_SENT; break;
        case 2: M = 200;  atype = 0; bias = bq_pass; W = w2; C = wsf + OFF_WQ_PASS; break;
        case 3: M = 2560; atype = 1; bias = nullptr; W = w3; C = wsf + OFF_UH_WORD; break;
        case 4: M = 1600; atype = 2; bias = nullptr; W = w4; C = wsf + OFF_UH_SRC;  break;
        default: M = 64;  atype = 3; bias = nullptr; W = w5; C = wsf + OFF_UH_SENT; break;
    }
    int m0 = by * 64, n0 = bx * 64;

    int lane = tid & 63, wvx = tid >> 6, quad = lane >> 4, l16 = lane & 15;
    int sm = tid >> 2, koff = (tid & 3) * 8;            // A staging: row, 8-chunk
    int rW = tid >> 3, cW = (tid & 7) * 8;              // W staging: k-row, 8 n-cols
    int rWs = rW * 68 + (cW ^ (((rW >> 3) & 3) << 4));  // swizzled Wtmp write base
    int nB = tid >> 2, kB8 = (tid & 3) * 8;             // Bt builder: n-row, 8 k
    int colp = nB ^ (((kB8 >> 3) & 3) << 4);            // swizzled Wtmp read col

    short* At = (short*)smemf;
    short* Bt = (short*)(smemf + 1024);
    float* Wtmp = smemf + 2048;                         // [32][68] f32, col-swizzled

    // A-row gather base (row -> global f32 pointer per segment type)
    const float* arow = nullptr;
    {
        int rr = m0 + sm;
        if (rr < M) {
            if (atype == 0) arow = source + rr * D_;
            else if (atype == 1) { int b = rr / NW_; int j = rr - b * NW_;
                                   int se = j / WORDS_; int wd = j - se * WORDS_;
                                   arow = qa_word_bank + ((wd * B_ + b) * SENTS_ + se) * D_; }
            else if (atype == 2) { int b = rr / SRC_; int j = rr - b * SRC_;
                                   arow = src_bank + (j * B_ + b) * D_; }
            else                 { int b = rr >> 4; int s2 = rr & 15;
                                   arow = qa_sent_bank + (s2 * B_ + b) * D_; }
        }
    }
    const float* wbase = W + n0 + cW;

    auto loadA = [&](float* r, int kk) {
        if (arow) {
            float4 f0 = *(const float4*)(arow + kk * 32 + koff);
            float4 f1 = *(const float4*)(arow + kk * 32 + koff + 4);
            r[0]=f0.x; r[1]=f0.y; r[2]=f0.z; r[3]=f0.w;
            r[4]=f1.x; r[5]=f1.y; r[6]=f1.z; r[7]=f1.w;
        } else {
#pragma unroll
            for (int i = 0; i < 8; ++i) r[i] = 0.f;
        }
    };
    auto loadW = [&](float* r, int kk) {
        const float* p = wbase + (kk * 32 + rW) * D_;
        float4 f0 = *(const float4*)p;
        float4 f1 = *(const float4*)(p + 4);
        r[0]=f0.x; r[1]=f0.y; r[2]=f0.z; r[3]=f0.w;
        r[4]=f1.x; r[5]=f1.y; r[6]=f1.z; r[7]=f1.w;
    };
    auto storeWtmp = [&](const float* r) {
        *(float4*)(Wtmp + rWs)     = float4{r[0], r[1], r[2], r[3]};
        *(float4*)(Wtmp + rWs + 4) = float4{r[4], r[5], r[6], r[7]};
    };
    auto storeAt = [&](const float* r) {
        union { ushort_t u[8]; int4 v; } pk;
#pragma unroll
        for (int i = 0; i < 8; ++i) pk.u[i] = f2b(r[i]);
        *(int4*)(At + sm * 32 + koff) = pk.v;
    };
    auto buildBt = [&]() {
        union { ushort_t u[8]; int4 v; } pk;
#pragma unroll
        for (int i = 0; i < 8; ++i) pk.u[i] = f2b(Wtmp[(kB8 + i) * 68 + colp]);
        *(int4*)(Bt + nB * 32 + kB8) = pk.v;
    };

    f4v acc[4] = { {0.f,0.f,0.f,0.f}, {0.f,0.f,0.f,0.f},
                   {0.f,0.f,0.f,0.f}, {0.f,0.f,0.f,0.f} };

    // prologue: Wtmp <- W(0); prefetch W(1), A(0), A(1)
    float ac[8], an[8], wn[8];
    loadA(ac, 0);
    {
        float w0r[8];
        loadW(w0r, 0);
        storeWtmp(w0r);
    }
    loadW(wn, 1);
    loadA(an, 1);
    __syncthreads();

    for (int kk = 0; kk < 16; ++kk) {
        // phase1: build At (A tile kk) and Bt (transpose of Wtmp = W tile kk)
        storeAt(ac);
        buildBt();
        __syncthreads();
        // phase2: stage next W tile, issue prefetches, MFMA on current tiles
        if (kk < 15) storeWtmp(wn);          // W tile kk+1 (reads of tile kk done)
        if (kk < 14) loadW(wn, kk + 2);
        if (kk < 15) {
#pragma unroll
            for (int i = 0; i < 8; ++i) ac[i] = an[i];
        }
        if (kk < 14) loadA(an, kk + 2);
        s8v af = *(const s8v*)(At + (wvx * 16 + l16) * 32 + quad * 8);
#pragma unroll
        for (int ng = 0; ng < 4; ++ng) {
            s8v bf = *(const s8v*)(Bt + (ng * 16 + l16) * 32 + quad * 8);
            acc[ng] = __builtin_amdgcn_mfma_f32_16x16x32_bf16(af, bf, acc[ng], 0, 0, 0);
        }
        __syncthreads();
    }

    // epilogue: pre-scale by 2*log2e so k2 can use exp2 directly.
#pragma unroll
    for (int ng = 0; ng < 4; ++ng) {
        int col = n0 + ng * 16 + l16;
        float bb = bias ? bias[col] : 0.f;
#pragma unroll
        for (int rr2 = 0; rr2 < 4; ++rr2) {
            int row = m0 + wvx * 16 + quad * 4 + rr2;
            if (row < M) C[row * D_ + col] = (acc[ng][rr2] + bb) * C2L2E;
        }
    }
}

// ---------------- k2: additive-attention scores — 5 wave-fifths per job ----------------
// 5280 blocks x 4 waves = 21120 wave-fifths (R7, proven). Masked jobs exit.
// score = Vsum - 2*sum_d v[d]*sigmoid(-2x); exp(2x)=exp2(pre-scaled sum).
__global__ __launch_bounds__(256) void k2_scores(
    const float* __restrict__ v_word, const float* __restrict__ v_sent,
    const float* __restrict__ v_pass,
    const int* __restrict__ src_lengths, const int* __restrict__ qa_word_lengths,
    float* __restrict__ wsf)
{
    int lane = threadIdx.x & 63;
    int jid = blockIdx.x * 4 + (threadIdx.x >> 6);   // 21120 wave-fifths, exact
    int job = jid / 5, fifth = jid - job * 5;
    int b = job / NJOB_, slot = job - b * NJOB_;
    const float* uh; const float* v; const float* wq; float* out; int ostride;
    if (slot < SRC_) {
        if (slot >= src_lengths[b]) return;           // masked: value never read
        uh = wsf + OFF_UH_SRC + (size_t)(b * SRC_ + slot) * D_;
        v = v_pass; wq = wsf + OFF_WQ_PASS + b * T_ * D_;
        out = wsf + OFF_SC_SRC + b * T_ * SRC_ + slot; ostride = SRC_;
    } else if (slot < NMEM_) {
        int j = slot - SRC_;
        int se = j / WORDS_; int wd = j - se * WORDS_;
        if (wd >= qa_word_lengths[b * SENTS_ + se]) return;  // masked
        uh = wsf + OFF_UH_WORD + (size_t)(b * NW_ + j) * D_;
        v = v_word; wq = wsf + OFF_WQ_WORD + b * T_ * D_;
        out = wsf + OFF_SC_WORD + b * T_ * NW_ + j; ostride = NW_;
    } else {
        int s2 = slot - NMEM_;
        uh = wsf + OFF_UH_SENT + (size_t)(b * SENTS_ + s2) * D_;
        v = v_sent; wq = wsf + OFF_WQ_SENT + b * T_ * D_;
        out = wsf + OFF_SC_SENT + b * T_ * SENTS_ + s2; ostride = SENTS_;
    }
    int d0 = lane * 8;
    float4 u0 = *(const float4*)(uh + d0);
    float4 u1 = *(const float4*)(uh + d0 + 4);
    float uhr[8] = {u0.x, u0.y, u0.z, u0.w, u1.x, u1.y, u1.z, u1.w};
    float4 v0 = *(const float4*)(v + d0);
    float4 v1 = *(const float4*)(v + d0 + 4);
    float vr[8] = {v0.x, v0.y, v0.z, v0.w, v1.x, v1.y, v1.z, v1.w};

    // Vsum = sum_d v[d] (broadcast to all lanes)
    float vs = ((vr[0] + vr[1]) + (vr[2] + vr[3])) + ((vr[4] + vr[5]) + (vr[6] + vr[7]));
#pragma unroll
    for (int off = 32; off > 0; off >>= 1) vs += __shfl_xor(vs, off, 64);

    const float* wqh = wq + (fifth * 10) * D_ + d0;
    int tbase = fifth * 10;
#pragma unroll 1
    for (int g = 0; g < 2; ++g) {
        float a5[5];
#pragma unroll
        for (int u5 = 0; u5 < 5; ++u5) {
            const float* wr = wqh + (g * 5 + u5) * D_;
            float4 w0 = *(const float4*)(wr);
            float4 w1 = *(const float4*)(wr + 4);
            float wrr[8] = {w0.x, w0.y, w0.z, w0.w, w1.x, w1.y, w1.z, w1.w};
            float a = 0.f;
#pragma unroll
            for (int j = 0; j < 8; ++j) {
                float e = __builtin_amdgcn_exp2f(wrr[j] + uhr[j]);  // exp(2x)
                float r = __builtin_amdgcn_rcpf(e + 1.f);           // sigmoid(-2x)
                a = fmaf(vr[j], r, a);
            }
            a5[u5] = a;
        }
        // 5 interleaved butterfly reductions (all indices static -> registers)
#pragma unroll
        for (int off = 32; off > 0; off >>= 1) {
#pragma unroll
            for (int u5 = 0; u5 < 5; ++u5) a5[u5] += __shfl_xor(a5[u5], off, 64);
        }
        if (lane == 0) {
#pragma unroll
            for (int u5 = 0; u5 < 5; ++u5)
                out[(tbase + g * 5 + u5) * ostride] = fmaf(-2.f, a5[u5], vs);
        }
    }
}

// ---------------- k3ac: fused softmax + f32 context GEMV ----------------
// One block per (b,t). Phase 1: hier combine + mask + softmax (identical math
// to the proven k3a) -> normalized f32 p[1056] in LDS (masked slots exactly
// 0.0f via exp underflow). Phase 2: GEMV over the ORIGINAL f32 banks,
// d-contiguous (thread owns 2 adjacent d-cols -> coalesced float2 loads),
// iterating each segment's length rounded up to 4 (bit-exact: p=0 there).
__global__ __launch_bounds__(256) void k3ac(
    const int* __restrict__ src_lengths, const int* __restrict__ qa_word_lengths,
    const float* __restrict__ wsf,
    const float* __restrict__ src_bank, const float* __restrict__ qa_word_bank,
    float* __restrict__ out)
{
    __shared__ float p[NMEM_];
    __shared__ float red[4];
    int tid = threadIdx.x, lane = tid & 63, wv = tid >> 6;
    int bt = blockIdx.x, b = bt / T_, t = bt - b * T_;
    const float* sc_src  = wsf + OFF_SC_SRC  + bt * SRC_;
    const float* sc_word = wsf + OFF_SC_WORD + bt * NW_;
    const float* sc_sent = wsf + OFF_SC_SENT + bt * SENTS_;
    int slen = src_lengths[b];

    // ---- phase 1: combine + mask + softmax (k3a-identical) ----
    float mx = -3.0e38f;
    for (int j = tid; j < NMEM_; j += 256) {
        float val;
        if (j < SRC_) {
            val = (j < slen) ? sc_src[j] : -1e30f;
        } else {
            int jj = j - SRC_; int se = jj / WORDS_; int wd = jj - se * WORDS_;
            float raw = sc_word[jj] * sc_sent[se];
            val = (wd < qa_word_lengths[b * SENTS_ + se]) ? raw : -1e30f;
        }
        p[j] = val;
        mx = fmaxf(mx, val);
    }
#pragma unroll
    for (int off = 32; off > 0; off >>= 1) mx = fmaxf(mx, __shfl_xor(mx, off, 64));
    if (lane == 0) red[wv] = mx;
    __syncthreads();
    mx = fmaxf(fmaxf(red[0], red[1]), fmaxf(red[2], red[3]));
    __syncthreads();
    float lsum = 0.f;
    for (int j = tid; j < NMEM_; j += 256) {
        float e = __expf(p[j] - mx);   // masked: exp(-1e30-mx) underflows to 0.0f
        p[j] = e; lsum += e;
    }
#pragma unroll
    for (int off = 32; off > 0; off >>= 1) lsum += __shfl_xor(lsum, off, 64);
    if (lane == 0) red[wv] = lsum;
    __syncthreads();
    float inv = 1.f / (red[0] + red[1] + red[2] + red[3]);
    for (int j = tid; j < NMEM_; j += 256) p[j] *= inv;
    __syncthreads();

    // ---- phase 2: context GEMV, thread owns cols d0, d0+1 ----
    int d0 = tid * 2;
    float acc0 = 0.f, acc1 = 0.f;
    // src segment: memory[s][d] = src_bank[(s*B+b)*D + d], s-stride B*D
    {
        int slen4 = (slen + 3) & ~3;               // p==0 beyond slen (bit-exact)
        const float* bank = src_bank + (size_t)b * D_ + d0;
        for (int s = 0; s < slen4; s += 4) {
            float4 pv = *(const float4*)(p + s);
            const float* r0 = bank + (size_t)s * (B_ * D_);
            float2 m0 = *(const float2*)(r0);
            float2 m1 = *(const float2*)(r0 + B_ * D_);
            float2 m2 = *(const float2*)(r0 + 2 * B_ * D_);
            float2 m3 = *(const float2*)(r0 + 3 * B_ * D_);
            acc0 = fmaf(pv.x, m0.x, acc0); acc1 = fmaf(pv.x, m0.y, acc1);
            acc0 = fmaf(pv.y, m1.x, acc0); acc1 = fmaf(pv.y, m1.y, acc1);
            acc0 = fmaf(pv.z, m2.x, acc0); acc1 = fmaf(pv.z, m2.y, acc1);
            acc0 = fmaf(pv.w, m3.x, acc0); acc1 = fmaf(pv.w, m3.y, acc1);
        }
    }
    // word segment: memory row jw=se*40+wd -> qa_word_bank[((wd*B+b)*SENTS+se)*D + d]
#pragma unroll 1
    for (int se = 0; se < SENTS_; ++se) {
        int lim = qa_word_lengths[b * SENTS_ + se];
        int lim4 = (lim + 3) & ~3;                 // p==0 beyond lim (bit-exact)
        const float* bank = qa_word_bank + ((size_t)b * SENTS_ + se) * D_ + d0;
        const float* pw = p + SRC_ + se * WORDS_;
        for (int wd = 0; wd < lim4; wd += 4) {
            float4 pv = *(const float4*)(pw + wd);
            const float* r0 = bank + (size_t)wd * (B_ * SENTS_ * D_);
            float2 m0 = *(const float2*)(r0);
            float2 m1 = *(const float2*)(r0 + B_ * SENTS_ * D_);
            float2 m2 = *(const float2*)(r0 + 2 * B_ * SENTS_ * D_);
            float2 m3 = *(const float2*)(r0 + 3 * B_ * SENTS_ * D_);
            acc0 = fmaf(pv.x, m0.x, acc0); acc1 = fmaf(pv.x, m0.y, acc1);
            acc0 = fmaf(pv.y, m1.x, acc0); acc1 = fmaf(pv.y, m1.y, acc1);
            acc0 = fmaf(pv.z, m2.x, acc0); acc1 = fmaf(pv.z, m2.y, acc1);
            acc0 = fmaf(pv.w, m3.x, acc0); acc1 = fmaf(pv.w, m3.y, acc1);
        }
    }
    *(float2*)(out + (size_t)(b * T_ + t) * D_ + d0) = float2{acc0, acc1};
}

extern "C" void kernel_launch(void* const* d_in, const int* in_sizes, int n_in,
                              void* d_out, int out_size, void* d_ws, size_t ws_size,
                              hipStream_t stream)
{
    (void)in_sizes; (void)n_in; (void)out_size; (void)ws_size;
    const float* source          = (const float*)d_in[0];
    const float* src_bank        = (const float*)d_in[1];
    const int*   src_lengths     = (const int*)d_in[2];
    const float* qa_sent_bank    = (const float*)d_in[3];
    /* d_in[4] qa_sent_lengths unused (matches reference) */
    const float* qa_word_bank    = (const float*)d_in[5];
    const int*   qa_word_lengths = (const int*)d_in[6];
    const float* Wq_word = (const float*)d_in[7];
    const float* bq_word = (const float*)d_in[8];
    const float* Uc_word = (const float*)d_in[9];
    const float* v_word  = (const float*)d_in[10];
    const float* Wq_sent = (const float*)d_in[11];
    const float* bq_sent = (const float*)d_in[12];
    const float* Uc_sent = (const float*)d_in[13];
    const float* v_sent  = (const float*)d_in[14];
    const float* Wq_pass = (const float*)d_in[15];
    const float* bq_pass = (const float*)d_in[16];
    const float* Uc_pass = (const float*)d_in[17];
    const float* v_pass  = (const float*)d_in[18];

    float* wsf = (float*)d_ws;
    float* out = (float*)d_out;

    // W order must match kA segment order:
    // 0:Wq_word 1:Wq_sent 2:Wq_pass 3:Uc_word 4:Uc_pass 5:Uc_sent
    kA<<<dim3(624), dim3(256), 0, stream>>>(
        source, src_bank, qa_sent_bank, qa_word_bank,
        Wq_word, Wq_sent, Wq_pass, Uc_word, Uc_pass, Uc_sent,
        bq_word, bq_sent, bq_pass, wsf);
    k2_scores<<<dim3(5280), dim3(256), 0, stream>>>(
        v_word, v_sent, v_pass, src_lengths, qa_word_lengths, wsf);
    k3ac<<<dim3(200), dim3(256), 0, stream>>>(
        src_lengths, qa_word_lengths, wsf, src_bank, qa_word_bank, out);
}

// Round 13
// 159.358 us; speedup vs baseline: 1.1816x; 1.1816x over previous
//
#include <hip/hip_runtime.h>
#include <hip/hip_bf16.h>

// HierarchicalAttention: B=4,T=50,D=512, SRC=400, SENTS=16, WORDS=40.
// 3-launch pipeline:
//   kA   projections via bf16 MFMA with INLINE weight transpose (624 blocks)
//   k2   tanh scores — R7's 5280-block wave-fifth split (proven)
//   k3ac FUSED softmax + f32 context GEMV — v2: 800 blocks ((b,t) x 4 d-slices,
//        softmax recomputed per slice: trivial), thread = (col, s-half),
//        8-row groups with depth-1 group prefetch (8 loads in flight), LDS
//        combine. R12 v1 at 200 blocks was latency-bound (55us, VALUBusy 4.5%).

#define B_    4
#define T_    50
#define D_    512
#define SRC_  400
#define SENTS_ 16
#define WORDS_ 40
#define NW_   640      // SENTS*WORDS
#define NMEM_ 1040     // SRC + NW
#define NJOB_ 1056     // NMEM + SENTS (score jobs per batch)

#define C2L2E 2.8853900817779268f   // 2*log2(e): x -> exp2(C2L2E*x) = exp(2x)

typedef unsigned short ushort_t;
using s8v = __attribute__((ext_vector_type(8))) short;   // 8 bf16 (4 VGPRs)
using f4v = __attribute__((ext_vector_type(4))) float;   // MFMA accumulator

// ---- workspace layout ----
// f32 region (float offsets):
#define OFF_WQ_WORD 0
#define OFF_WQ_SENT 102400
#define OFF_WQ_PASS 204800
#define OFF_UH_SRC  307200
#define OFF_UH_WORD 1126400
#define OFF_UH_SENT 2437120
#define OFF_SC_SRC  2469888
#define OFF_SC_WORD 2549888
#define OFF_SC_SENT 2677888

__device__ __forceinline__ ushort_t f2b(float f) {
    __hip_bfloat16 h = __float2bfloat16(f);   // RNE
    return *(ushort_t*)&h;
}

// ---------------- kA: projections with inline weight transpose ----------------
// 624 compact GEMM blocks (z0-2: 32 each M=200, z3: 320 M=2560, z4: 200 M=1600,
// z5: 8 M=64). Block tile 64x64, K=512 in 16 steps. Per step, the W[k][n] f32
// tile is staged to LDS (Wtmp, col-swizzled), transposed + converted to bf16 Bt
// in-block; A rows converted to At. 2 barriers/step; depth-2 register prefetch.
__global__ __launch_bounds__(256) void kA(
    const float* __restrict__ source, const float* __restrict__ src_bank,
    const float* __restrict__ qa_sent_bank, const float* __restrict__ qa_word_bank,
    const float* __restrict__ w0, const float* __restrict__ w1,
    const float* __restrict__ w2, const float* __restrict__ w3,
    const float* __restrict__ w4, const float* __restrict__ w5,
    const float* __restrict__ bq_word, const float* __restrict__ bq_sent,
    const float* __restrict__ bq_pass,
    float* __restrict__ wsf)
{
    __shared__ float smemf[4224];   // At[0,1024) Bt[1024,2048) Wtmp[2048,4224)
    int bid = blockIdx.x;
    int tid = threadIdx.x;

    int z, rem;
    if (bid < 96)       { z = bid >> 5; rem = bid & 31; }
    else if (bid < 416) { z = 3; rem = bid - 96; }
    else if (bid < 616) { z = 4; rem = bid - 416; }
    else                { z = 5; rem = bid - 616; }
    int by = rem >> 3, bx = rem & 7;
    int M, atype; const float* bias; const float* W; float* C;
    switch (z) {
        case 0: M = 200;  atype = 0; bias = bq_word; W = w0; C = wsf + OFF_WQ_WORD; break;
        case 1: M = 200;  atype = 0; bias = bq_sent; W = w1; C = wsf + OFF_WQ_SENT; break;
        case 2: M = 200;  atype = 0; bias = bq_pass; W = w2; C = wsf + OFF_WQ_PASS; break;
        case 3: M = 2560; atype = 1; bias = nullptr; W = w3; C = wsf + OFF_UH_WORD; break;
        case 4: M = 1600; atype = 2; bias = nullptr; W = w4; C = wsf + OFF_UH_SRC;  break;
        default: M = 64;  atype = 3; bias = nullptr; W = w5; C = wsf + OFF_UH_SENT; break;
    }
    int m0 = by * 64, n0 = bx * 64;

    int lane = tid & 63, wvx = tid >> 6, quad = lane >> 4, l16 = lane & 15;
    int sm = tid >> 2, koff = (tid & 3) * 8;            // A staging: row, 8-chunk
    int rW = tid >> 3, cW = (tid & 7) * 8;              // W staging: k-row, 8 n-cols
    int rWs = rW * 68 + (cW ^ (((rW >> 3) & 3) << 4));  // swizzled Wtmp write base
    int nB = tid >> 2, kB8 = (tid & 3) * 8;             // Bt builder: n-row, 8 k
    int colp = nB ^ (((kB8 >> 3) & 3) << 4);            // swizzled Wtmp read col

    short* At = (short*)smemf;
    short* Bt = (short*)(smemf + 1024);
    float* Wtmp = smemf + 2048;                         // [32][68] f32, col-swizzled

    // A-row gather base (row -> global f32 pointer per segment type)
    const float* arow = nullptr;
    {
        int rr = m0 + sm;
        if (rr < M) {
            if (atype == 0) arow = source + rr * D_;
            else if (atype == 1) { int b = rr / NW_; int j = rr - b * NW_;
                                   int se = j / WORDS_; int wd = j - se * WORDS_;
                                   arow = qa_word_bank + ((wd * B_ + b) * SENTS_ + se) * D_; }
            else if (atype == 2) { int b = rr / SRC_; int j = rr - b * SRC_;
                                   arow = src_bank + (j * B_ + b) * D_; }
            else                 { int b = rr >> 4; int s2 = rr & 15;
                                   arow = qa_sent_bank + (s2 * B_ + b) * D_; }
        }
    }
    const float* wbase = W + n0 + cW;

    auto loadA = [&](float* r, int kk) {
        if (arow) {
            float4 f0 = *(const float4*)(arow + kk * 32 + koff);
            float4 f1 = *(const float4*)(arow + kk * 32 + koff + 4);
            r[0]=f0.x; r[1]=f0.y; r[2]=f0.z; r[3]=f0.w;
            r[4]=f1.x; r[5]=f1.y; r[6]=f1.z; r[7]=f1.w;
        } else {
#pragma unroll
            for (int i = 0; i < 8; ++i) r[i] = 0.f;
        }
    };
    auto loadW = [&](float* r, int kk) {
        const float* p = wbase + (kk * 32 + rW) * D_;
        float4 f0 = *(const float4*)p;
        float4 f1 = *(const float4*)(p + 4);
        r[0]=f0.x; r[1]=f0.y; r[2]=f0.z; r[3]=f0.w;
        r[4]=f1.x; r[5]=f1.y; r[6]=f1.z; r[7]=f1.w;
    };
    auto storeWtmp = [&](const float* r) {
        *(float4*)(Wtmp + rWs)     = float4{r[0], r[1], r[2], r[3]};
        *(float4*)(Wtmp + rWs + 4) = float4{r[4], r[5], r[6], r[7]};
    };
    auto storeAt = [&](const float* r) {
        union { ushort_t u[8]; int4 v; } pk;
#pragma unroll
        for (int i = 0; i < 8; ++i) pk.u[i] = f2b(r[i]);
        *(int4*)(At + sm * 32 + koff) = pk.v;
    };
    auto buildBt = [&]() {
        union { ushort_t u[8]; int4 v; } pk;
#pragma unroll
        for (int i = 0; i < 8; ++i) pk.u[i] = f2b(Wtmp[(kB8 + i) * 68 + colp]);
        *(int4*)(Bt + nB * 32 + kB8) = pk.v;
    };

    f4v acc[4] = { {0.f,0.f,0.f,0.f}, {0.f,0.f,0.f,0.f},
                   {0.f,0.f,0.f,0.f}, {0.f,0.f,0.f,0.f} };

    // prologue: Wtmp <- W(0); prefetch W(1), A(0), A(1)
    float ac[8], an[8], wn[8];
    loadA(ac, 0);
    {
        float w0r[8];
        loadW(w0r, 0);
        storeWtmp(w0r);
    }
    loadW(wn, 1);
    loadA(an, 1);
    __syncthreads();

    for (int kk = 0; kk < 16; ++kk) {
        // phase1: build At (A tile kk) and Bt (transpose of Wtmp = W tile kk)
        storeAt(ac);
        buildBt();
        __syncthreads();
        // phase2: stage next W tile, issue prefetches, MFMA on current tiles
        if (kk < 15) storeWtmp(wn);          // W tile kk+1 (reads of tile kk done)
        if (kk < 14) loadW(wn, kk + 2);
        if (kk < 15) {
#pragma unroll
            for (int i = 0; i < 8; ++i) ac[i] = an[i];
        }
        if (kk < 14) loadA(an, kk + 2);
        s8v af = *(const s8v*)(At + (wvx * 16 + l16) * 32 + quad * 8);
#pragma unroll
        for (int ng = 0; ng < 4; ++ng) {
            s8v bf = *(const s8v*)(Bt + (ng * 16 + l16) * 32 + quad * 8);
            acc[ng] = __builtin_amdgcn_mfma_f32_16x16x32_bf16(af, bf, acc[ng], 0, 0, 0);
        }
        __syncthreads();
    }

    // epilogue: pre-scale by 2*log2e so k2 can use exp2 directly.
#pragma unroll
    for (int ng = 0; ng < 4; ++ng) {
        int col = n0 + ng * 16 + l16;
        float bb = bias ? bias[col] : 0.f;
#pragma unroll
        for (int rr2 = 0; rr2 < 4; ++rr2) {
            int row = m0 + wvx * 16 + quad * 4 + rr2;
            if (row < M) C[row * D_ + col] = (acc[ng][rr2] + bb) * C2L2E;
        }
    }
}

// ---------------- k2: additive-attention scores — 5 wave-fifths per job ----------------
// 5280 blocks x 4 waves = 21120 wave-fifths (R7, proven). Masked jobs exit.
// score = Vsum - 2*sum_d v[d]*sigmoid(-2x); exp(2x)=exp2(pre-scaled sum).
__global__ __launch_bounds__(256) void k2_scores(
    const float* __restrict__ v_word, const float* __restrict__ v_sent,
    const float* __restrict__ v_pass,
    const int* __restrict__ src_lengths, const int* __restrict__ qa_word_lengths,
    float* __restrict__ wsf)
{
    int lane = threadIdx.x & 63;
    int jid = blockIdx.x * 4 + (threadIdx.x >> 6);   // 21120 wave-fifths, exact
    int job = jid / 5, fifth = jid - job * 5;
    int b = job / NJOB_, slot = job - b * NJOB_;
    const float* uh; const float* v; const float* wq; float* out; int ostride;
    if (slot < SRC_) {
        if (slot >= src_lengths[b]) return;           // masked: value never read
        uh = wsf + OFF_UH_SRC + (size_t)(b * SRC_ + slot) * D_;
        v = v_pass; wq = wsf + OFF_WQ_PASS + b * T_ * D_;
        out = wsf + OFF_SC_SRC + b * T_ * SRC_ + slot; ostride = SRC_;
    } else if (slot < NMEM_) {
        int j = slot - SRC_;
        int se = j / WORDS_; int wd = j - se * WORDS_;
        if (wd >= qa_word_lengths[b * SENTS_ + se]) return;  // masked
        uh = wsf + OFF_UH_WORD + (size_t)(b * NW_ + j) * D_;
        v = v_word; wq = wsf + OFF_WQ_WORD + b * T_ * D_;
        out = wsf + OFF_SC_WORD + b * T_ * NW_ + j; ostride = NW_;
    } else {
        int s2 = slot - NMEM_;
        uh = wsf + OFF_UH_SENT + (size_t)(b * SENTS_ + s2) * D_;
        v = v_sent; wq = wsf + OFF_WQ_SENT + b * T_ * D_;
        out = wsf + OFF_SC_SENT + b * T_ * SENTS_ + s2; ostride = SENTS_;
    }
    int d0 = lane * 8;
    float4 u0 = *(const float4*)(uh + d0);
    float4 u1 = *(const float4*)(uh + d0 + 4);
    float uhr[8] = {u0.x, u0.y, u0.z, u0.w, u1.x, u1.y, u1.z, u1.w};
    float4 v0 = *(const float4*)(v + d0);
    float4 v1 = *(const float4*)(v + d0 + 4);
    float vr[8] = {v0.x, v0.y, v0.z, v0.w, v1.x, v1.y, v1.z, v1.w};

    // Vsum = sum_d v[d] (broadcast to all lanes)
    float vs = ((vr[0] + vr[1]) + (vr[2] + vr[3])) + ((vr[4] + vr[5]) + (vr[6] + vr[7]));
#pragma unroll
    for (int off = 32; off > 0; off >>= 1) vs += __shfl_xor(vs, off, 64);

    const float* wqh = wq + (fifth * 10) * D_ + d0;
    int tbase = fifth * 10;
#pragma unroll 1
    for (int g = 0; g < 2; ++g) {
        float a5[5];
#pragma unroll
        for (int u5 = 0; u5 < 5; ++u5) {
            const float* wr = wqh + (g * 5 + u5) * D_;
            float4 w0 = *(const float4*)(wr);
            float4 w1 = *(const float4*)(wr + 4);
            float wrr[8] = {w0.x, w0.y, w0.z, w0.w, w1.x, w1.y, w1.z, w1.w};
            float a = 0.f;
#pragma unroll
            for (int j = 0; j < 8; ++j) {
                float e = __builtin_amdgcn_exp2f(wrr[j] + uhr[j]);  // exp(2x)
                float r = __builtin_amdgcn_rcpf(e + 1.f);           // sigmoid(-2x)
                a = fmaf(vr[j], r, a);
            }
            a5[u5] = a;
        }
        // 5 interleaved butterfly reductions (all indices static -> registers)
#pragma unroll
        for (int off = 32; off > 0; off >>= 1) {
#pragma unroll
            for (int u5 = 0; u5 < 5; ++u5) a5[u5] += __shfl_xor(a5[u5], off, 64);
        }
        if (lane == 0) {
#pragma unroll
            for (int u5 = 0; u5 < 5; ++u5)
                out[(tbase + g * 5 + u5) * ostride] = fmaf(-2.f, a5[u5], vs);
        }
    }
}

// ---------------- k3ac v2: fused softmax + f32 context GEMV (800 blocks) ----------------
// Block = (bt, dq): bt = bid>>2, d-slice dq = bid&3 (128 cols). Phase 1: full
// softmax into LDS p[1040] (4x redundant across d-slices — trivial cost).
// Phase 2: thread = (col c = tid&127, s-half sh = tid>>7); 8-row groups with
// depth-1 group prefetch (8 independent loads in flight during the FMA drain);
// lengths rounded to 8 (p exactly 0.0 in the pad — bit-exact). LDS combine of
// the two s-half partials; 128-thread coalesced store.
__global__ __launch_bounds__(256) void k3ac(
    const int* __restrict__ src_lengths, const int* __restrict__ qa_word_lengths,
    const float* __restrict__ wsf,
    const float* __restrict__ src_bank, const float* __restrict__ qa_word_bank,
    float* __restrict__ out)
{
    __shared__ float p[NMEM_];
    __shared__ float part[256];
    __shared__ float red[4];
    int tid = threadIdx.x, lane = tid & 63, wv = tid >> 6;
    int bid = blockIdx.x;
    int bt = bid >> 2, dq = bid & 3;
    int b = bt / T_, t = bt - b * T_;
    const float* sc_src  = wsf + OFF_SC_SRC  + bt * SRC_;
    const float* sc_word = wsf + OFF_SC_WORD + bt * NW_;
    const float* sc_sent = wsf + OFF_SC_SENT + bt * SENTS_;
    int slen = src_lengths[b];

    // ---- phase 1: combine + mask + softmax (k3a-identical math) ----
    float mx = -3.0e38f;
    for (int j = tid; j < NMEM_; j += 256) {
        float val;
        if (j < SRC_) {
            val = (j < slen) ? sc_src[j] : -1e30f;
        } else {
            int jj = j - SRC_; int se = jj / WORDS_; int wd = jj - se * WORDS_;
            float raw = sc_word[jj] * sc_sent[se];
            val = (wd < qa_word_lengths[b * SENTS_ + se]) ? raw : -1e30f;
        }
        p[j] = val;
        mx = fmaxf(mx, val);
    }
#pragma unroll
    for (int off = 32; off > 0; off >>= 1) mx = fmaxf(mx, __shfl_xor(mx, off, 64));
    if (lane == 0) red[wv] = mx;
    __syncthreads();
    mx = fmaxf(fmaxf(red[0], red[1]), fmaxf(red[2], red[3]));
    __syncthreads();
    float lsum = 0.f;
    for (int j = tid; j < NMEM_; j += 256) {
        float e = __expf(p[j] - mx);   // masked: exp underflows to exactly 0.0f
        p[j] = e; lsum += e;
    }
#pragma unroll
    for (int off = 32; off > 0; off >>= 1) lsum += __shfl_xor(lsum, off, 64);
    if (lane == 0) red[wv] = lsum;
    __syncthreads();
    float inv = 1.f / (red[0] + red[1] + red[2] + red[3]);
    for (int j = tid; j < NMEM_; j += 256) p[j] *= inv;
    __syncthreads();

    // ---- phase 2: GEMV slice, col c of this 128-col d-slice, s-half sh ----
    int c = tid & 127, sh = tid >> 7;
    int d = dq * 128 + c;
    float acc = 0.f;

    // accumulate a row range [r0,r1) of a bank with row stride `strd` (floats),
    // probabilities pseg[r]; r1-r0 multiple of 8; 8 loads in flight.
    auto gemv8 = [&](const float* bank, int strd, const float* pseg, int r0, int r1) {
        if (r0 >= r1) return;
        const float* rp = bank + (size_t)r0 * strd;
        float m0 = rp[0], m1 = rp[strd], m2 = rp[2*strd], m3 = rp[3*strd];
        float m4 = rp[4*strd], m5 = rp[5*strd], m6 = rp[6*strd], m7 = rp[7*strd];
        float4 pa = *(const float4*)(pseg + r0);
        float4 pb = *(const float4*)(pseg + r0 + 4);
        for (int r = r0; r + 8 < r1; r += 8) {
            const float* np = bank + (size_t)(r + 8) * strd;
            float n0 = np[0], n1 = np[strd], n2 = np[2*strd], n3 = np[3*strd];
            float n4 = np[4*strd], n5 = np[5*strd], n6 = np[6*strd], n7 = np[7*strd];
            float4 qa = *(const float4*)(pseg + r + 8);
            float4 qb = *(const float4*)(pseg + r + 12);
            acc = fmaf(pa.x, m0, acc); acc = fmaf(pa.y, m1, acc);
            acc = fmaf(pa.z, m2, acc); acc = fmaf(pa.w, m3, acc);
            acc = fmaf(pb.x, m4, acc); acc = fmaf(pb.y, m5, acc);
            acc = fmaf(pb.z, m6, acc); acc = fmaf(pb.w, m7, acc);
            m0 = n0; m1 = n1; m2 = n2; m3 = n3;
            m4 = n4; m5 = n5; m6 = n6; m7 = n7;
            pa = qa; pb = qb;
        }
        acc = fmaf(pa.x, m0, acc); acc = fmaf(pa.y, m1, acc);
        acc = fmaf(pa.z, m2, acc); acc = fmaf(pa.w, m3, acc);
        acc = fmaf(pb.x, m4, acc); acc = fmaf(pb.y, m5, acc);
        acc = fmaf(pb.z, m6, acc); acc = fmaf(pb.w, m7, acc);
    };

    // src segment: row s -> src_bank[(s*B+b)*D + d], stride B*D floats.
    {
        int slen8 = (slen + 7) & ~7;              // p==0 beyond slen (bit-exact)
        const float* bank = src_bank + (size_t)b * D_ + d;
        int s0 = (sh == 0) ? 0 : 200;
        int s1 = (sh == 0) ? min(slen8, 200) : slen8;   // 200 = 8*25
        gemv8(bank, B_ * D_, p, s0, s1);
    }
    // word segment: se-range per half; row wd -> qa_word_bank[((wd*B+b)*SENTS+se)*D + d]
#pragma unroll 1
    for (int se = sh * 8; se < sh * 8 + 8; ++se) {
        int lim = qa_word_lengths[b * SENTS_ + se];
        int lim8 = (lim + 7) & ~7;                // p==0 beyond lim (bit-exact)
        const float* bank = qa_word_bank + ((size_t)b * SENTS_ + se) * D_ + d;
        gemv8(bank, B_ * SENTS_ * D_, p + SRC_ + se * WORDS_, 0, lim8);
    }

    part[tid] = acc;
    __syncthreads();
    if (tid < 128)
        out[(size_t)(b * T_ + t) * D_ + dq * 128 + tid] = part[tid] + part[tid + 128];
}

extern "C" void kernel_launch(void* const* d_in, const int* in_sizes, int n_in,
                              void* d_out, int out_size, void* d_ws, size_t ws_size,
                              hipStream_t stream)
{
    (void)in_sizes; (void)n_in; (void)out_size; (void)ws_size;
    const float* source          = (const float*)d_in[0];
    const float* src_bank        = (const float*)d_in[1];
    const int*   src_lengths     = (const int*)d_in[2];
    const float* qa_sent_bank    = (const float*)d_in[3];
    /* d_in[4] qa_sent_lengths unused (matches reference) */
    const float* qa_word_bank    = (const float*)d_in[5];
    const int*   qa_word_lengths = (const int*)d_in[6];
    const float* Wq_word = (const float*)d_in[7];
    const float* bq_word = (const float*)d_in[8];
    const float* Uc_word = (const float*)d_in[9];
    const float* v_word  = (const float*)d_in[10];
    const float* Wq_sent = (const float*)d_in[11];
    const float* bq_sent = (const float*)d_in[12];
    const float* Uc_sent = (const float*)d_in[13];
    const float* v_sent  = (const float*)d_in[14];
    const float* Wq_pass = (const float*)d_in[15];
    const float* bq_pass = (const float*)d_in[16];
    const float* Uc_pass = (const float*)d_in[17];
    const float* v_pass  = (const float*)d_in[18];

    float* wsf = (float*)d_ws;
    float* out = (float*)d_out;

    // W order must match kA segment order:
    // 0:Wq_word 1:Wq_sent 2:Wq_pass 3:Uc_word 4:Uc_pass 5:Uc_sent
    kA<<<dim3(624), dim3(256), 0, stream>>>(
        source, src_bank, qa_sent_bank, qa_word_bank,
        Wq_word, Wq_sent, Wq_pass, Uc_word, Uc_pass, Uc_sent,
        bq_word, bq_sent, bq_pass, wsf);
    k2_scores<<<dim3(5280), dim3(256), 0, stream>>>(
        v_word, v_sent, v_pass, src_lengths, qa_word_lengths, wsf);
    k3ac<<<dim3(800), dim3(256), 0, stream>>>(
        src_lengths, qa_word_lengths, wsf, src_bank, qa_word_bank, out);
}